// Round 1
// baseline (866.826 us; speedup 1.0000x reference)
//
#include <hip/hip_runtime.h>
#include <math.h>

// ---------------------------------------------------------------------------
// HybridGNN on MI355X.
// Pipeline:
//   L0 (gather):  fused gather(type_embed/rw_embed) + mean + 2x[100x50] matvec
//                 + relu for every level-0 pair of all three views, both t.
//   L1..L3:       same aggregation on dense workspace arrays.
//   attn:         per-batch-row fused view-attn (seq T=2), meta-attn (seq 3),
//                 pooling, edgetype select, reflect matvec, residual, L2 norm.
// Workspace layout (rows of 100 f32):
//   schema1 per t: L0 arrays {1,3,15,105}B at +{0,1,4,19}B, L1 {1,3,15}B at
//   +124B+{0,1,4}B, L2 {1,3}B at +143B+{0,1}B  -> 147B rows per t (t stride).
//   schema0: rows 294B + t*4B + {0,1}B.  random: rows 302B + {0,1}B.
//   spec [B][2][2][100] at row 306B; rview [B][100] after it.  Total ~64 MB.
// ---------------------------------------------------------------------------

#define NBATCH 512
#define TOTALP 1086

struct Seg {
  const float* emb;     // gather mode embedding base (null => dense mode)
  const float* selfp;   // dense self rows [N][100]
  const float* neighp;  // dense neighbor rows [N*r][100]
  const int*   ids_s;   // gather: self id array
  const int*   ids_n;   // gather: neighbor id array
  const float* Ws;      // [100][50]
  const float* Wn;      // [100][50]
  float*       outp;    // out row j at outp + j*ostride
  int ss, so;           // self id per-b stride, offset
  int ns, no;           // neigh id per-b stride, offset
  int estride;          // node stride in emb (elements)
  int ostride;
  int c;                // self rows per batch element
  int r;                // fanout
  int rows;             // = c*NBATCH
  int row_begin;        // prefix in fused row space
};

struct KArgs { Seg seg[14]; int n; };

// One block (128 thr) per output row: gather/load self + mean(neigh), then
// out[0:50]=relu(s@Ws), out[50:100]=relu(m@Wn).
__global__ __launch_bounds__(128) void agg_kernel(KArgs P) {
  __shared__ float s_sh[100];
  __shared__ float m_sh[100];
  __shared__ int   ids_sh[16];
  const int blk = blockIdx.x;
  int si = 0;
  for (int i = 1; i < P.n; ++i)
    if (blk >= P.seg[i].row_begin) si = i;
  const Seg& sg = P.seg[si];
  const int j   = blk - sg.row_begin;
  const int tid = threadIdx.x;
  const int c = sg.c, r = sg.r;
  const int b = j / c, pos = j - b * c;

  if (sg.emb) {
    if (tid == 0) ids_sh[15] = sg.ids_s[(long)b * sg.ss + sg.so + pos];
    if (tid < r)  ids_sh[tid] = sg.ids_n[(long)b * sg.ns + sg.no + pos * r + tid];
    __syncthreads();
    if (tid < 100) {
      s_sh[tid] = sg.emb[(long)ids_sh[15] * sg.estride + tid];
      float acc = 0.f;
      for (int q = 0; q < r; ++q)
        acc += sg.emb[(long)ids_sh[q] * sg.estride + tid];
      m_sh[tid] = acc / (float)r;
    }
  } else {
    __syncthreads();  // keep barrier count uniform across modes
    if (tid < 100) {
      s_sh[tid] = sg.selfp[(long)j * 100 + tid];
      float acc = 0.f;
      for (int q = 0; q < r; ++q)
        acc += sg.neighp[((long)j * r + q) * 100 + tid];
      m_sh[tid] = acc / (float)r;
    }
  }
  __syncthreads();
  if (tid < 100) {
    const float* W = (tid < 50) ? sg.Ws : sg.Wn;
    const float* x = (tid < 50) ? s_sh : m_sh;
    const int col = (tid < 50) ? tid : tid - 50;
    float acc = 0.f;
#pragma unroll 10
    for (int e = 0; e < 100; ++e) acc = fmaf(x[e], W[e * 50 + col], acc);
    sg.outp[(long)j * sg.ostride + tid] = fmaxf(acc, 0.f);
  }
}

// ---------------------------------------------------------------------------
// Attention step on LDS-resident x: rows i<n at xs[base + i*rs + d], d<100.
// q = LN(x)@Wq (only q is layernormed), k = x@Wk, v = x@Wv,
// attn = softmax(q.k^T/10), out = (attn@v)@Wf + x  (written back in place).
// ---------------------------------------------------------------------------
__device__ __forceinline__ void attn_step(
    float* xs, int base, int rs, int n,
    const float* Wq, const float* Wk, const float* Wv, const float* Wf,
    const float* g, const float* bb,
    float* ln, float* qq, float* kk, float* vv, float* ot,
    float* sc, float* musd, int tid)
{
  if (tid < n) {
    float mu = 0.f;
    for (int d = 0; d < 100; ++d) mu += xs[base + tid * rs + d];
    mu *= 0.01f;
    float var = 0.f;
    for (int d = 0; d < 100; ++d) {
      float t = xs[base + tid * rs + d] - mu; var = fmaf(t, t, var);
    }
    var *= 0.01f;
    musd[tid * 2]     = mu;
    musd[tid * 2 + 1] = rsqrtf(var + 1e-6f);
  }
  __syncthreads();
  for (int o = tid; o < n * 100; o += 128) {
    int i = o / 100, d = o - i * 100;
    ln[o] = (xs[base + i * rs + d] - musd[i * 2]) * musd[i * 2 + 1] * g[d] + bb[d];
  }
  __syncthreads();
  for (int o = tid; o < n * 100; o += 128) {
    int i = o / 100, d = o - i * 100;
    float aq = 0.f, ak = 0.f, av = 0.f;
    for (int e = 0; e < 100; ++e) {
      float xe = xs[base + i * rs + e];
      aq = fmaf(ln[i * 100 + e], Wq[e * 100 + d], aq);
      ak = fmaf(xe, Wk[e * 100 + d], ak);
      av = fmaf(xe, Wv[e * 100 + d], av);
    }
    qq[o] = aq; kk[o] = ak; vv[o] = av;
  }
  __syncthreads();
  if (tid < n * n) {
    int i = tid / n, u = tid - i * n;
    float s = 0.f;
    for (int d = 0; d < 100; ++d) s = fmaf(qq[i * 100 + d], kk[u * 100 + d], s);
    sc[tid] = s * 0.1f;  // q / sqrt(D=100)
  }
  __syncthreads();
  if (tid < n) {
    float mx = sc[tid * n];
    for (int u = 1; u < n; ++u) mx = fmaxf(mx, sc[tid * n + u]);
    float sm = 0.f;
    for (int u = 0; u < n; ++u) {
      float e = expf(sc[tid * n + u] - mx); sc[tid * n + u] = e; sm += e;
    }
    float inv = 1.f / sm;
    for (int u = 0; u < n; ++u) sc[tid * n + u] *= inv;
  }
  __syncthreads();
  for (int o = tid; o < n * 100; o += 128) {
    int i = o / 100, d = o - i * 100;
    float a = 0.f;
    for (int u = 0; u < n; ++u) a = fmaf(sc[i * n + u], vv[u * 100 + d], a);
    ot[o] = a;
  }
  __syncthreads();
  for (int o = tid; o < n * 100; o += 128) {
    int i = o / 100, d = o - i * 100;
    float a = 0.f;
    for (int e = 0; e < 100; ++e) a = fmaf(ot[i * 100 + e], Wf[e * 100 + d], a);
    ln[o] = a + xs[base + i * rs + d];  // residual; ln reused as temp
  }
  __syncthreads();
  for (int o = tid; o < n * 100; o += 128) {
    int i = o / 100, d = o - i * 100;
    xs[base + i * rs + d] = ln[o];
  }
  __syncthreads();
}

__global__ __launch_bounds__(128) void attn_final_kernel(
    const float* __restrict__ spec, const float* __restrict__ rview,
    const int* __restrict__ nodeids, const int* __restrict__ edgetype,
    const float* __restrict__ base_embed, const float* __restrict__ reflect,
    const float* vWq, const float* vWk, const float* vWv, const float* vWf,
    const float* vg, const float* vb,
    const float* mWq, const float* mWk, const float* mWv, const float* mWf,
    const float* mg, const float* mb,
    float* __restrict__ out)
{
  __shared__ float xs[600], ln[300], qq[300], kk[300], vv[300], ot[300];
  __shared__ float sc[16], musd[8], r200[200], pooled[200], nrm[1];
  const int b = blockIdx.x, tid = threadIdx.x;

  // xs[(v*2+t)*100+d]; views: 0=spec0, 1=spec1, 2=rview (same for both t)
  for (int o = tid; o < 600; o += 128) {
    int v = o / 200, rem = o - v * 200;
    xs[o] = (v < 2) ? spec[(long)b * 400 + o] : rview[(long)b * 100 + (rem % 100)];
  }
  __syncthreads();

  // view attention: batch (b,v), sequence over t (n=2)
  for (int v = 0; v < 3; ++v)
    attn_step(xs, v * 200, 100, 2, vWq, vWk, vWv, vWf, vg, vb,
              ln, qq, kk, vv, ot, sc, musd, tid);
  // meta attention: batch (b,t), sequence over v (n=3)
  for (int t = 0; t < 2; ++t)
    attn_step(xs, t * 100, 200, 3, mWq, mWk, mWv, mWf, mg, mb,
              ln, qq, kk, vv, ot, sc, musd, tid);

  for (int o = tid; o < 200; o += 128)
    pooled[o] = (xs[o] + xs[200 + o] + xs[400 + o]) * (1.f / 3.f);
  __syncthreads();

  const int et  = edgetype[NBATCH + b];   // edgetype[1][b]; edgetype[0] == arange(B)
  const long nid = nodeids[b];
  for (int o = tid; o < 200; o += 128) {
    float acc = base_embed[nid * 200 + o];
    const float* rf = reflect + (long)et * 20000 + o;  // reflect[et][d][o]
    const float* sl = pooled + et * 100;
    for (int d = 0; d < 100; ++d) acc = fmaf(sl[d], rf[d * 200], acc);
    r200[o] = acc;
  }
  __syncthreads();
  if (tid == 0) {
    float ss = 0.f;
    for (int o = 0; o < 200; ++o) ss = fmaf(r200[o], r200[o], ss);
    nrm[0] = 1.f / fmaxf(sqrtf(ss), 1e-12f);
  }
  __syncthreads();
  for (int o = tid; o < 200; o += 128)
    out[(long)b * 200 + o] = r200[o] * nrm[0];
}

// ---------------------------------------------------------------------------
extern "C" void kernel_launch(void* const* d_in, const int* in_sizes, int n_in,
                              void* d_out, int out_size, void* d_ws, size_t ws_size,
                              hipStream_t stream) {
  (void)in_sizes; (void)n_in; (void)out_size; (void)ws_size;
  const int*   nodeids          = (const int*)d_in[0];
  const int*   edgetype         = (const int*)d_in[1];
  const int*   neighbors        = (const int*)d_in[2];
  const int*   random_neighbors = (const int*)d_in[3];
  const float* base_embed       = (const float*)d_in[4];
  const float* type_embed       = (const float*)d_in[5];
  const float* rw_embed         = (const float*)d_in[6];
  const float* reflect          = (const float*)d_in[7];
  const float* agg0_self        = (const float*)d_in[8];
  const float* agg0_neigh       = (const float*)d_in[9];
  const float* agg1_self        = (const float*)d_in[10];
  const float* agg1_neigh       = (const float*)d_in[11];
  const float* rand_self        = (const float*)d_in[12];
  const float* rand_neigh       = (const float*)d_in[13];
  const float* vWq = (const float*)d_in[14];
  const float* vWk = (const float*)d_in[15];
  const float* vWv = (const float*)d_in[16];
  const float* vWf = (const float*)d_in[17];
  const float* vg  = (const float*)d_in[18];
  const float* vb  = (const float*)d_in[19];
  const float* mWq = (const float*)d_in[20];
  const float* mWk = (const float*)d_in[21];
  const float* mWv = (const float*)d_in[22];
  const float* mWf = (const float*)d_in[23];
  const float* mg  = (const float*)d_in[24];
  const float* mb  = (const float*)d_in[25];

  float* ws = (float*)d_ws;
  const long S1r = 147L * NBATCH;                 // schema1 rows per t
  auto rp = [&](long rows) { return ws + rows * 100; };
  float* spec_f  = ws + 306L * NBATCH * 100;      // [B][2][2][100]
  float* rview_f = spec_f + (long)NBATCH * 400;   // [B][100]

  const int  OFF1[4] = {18, 21, 36, 141};  // schema1 chunk offsets in TOTALP
  const int  FAN1[4] = {3, 5, 7, 9};
  const int  C1[4]   = {1, 3, 15, 105};
  const long CUM1[4]  = {0, 1, 4, 19};     // L0 array row offsets / NBATCH
  const long CUM1b[3] = {0, 1, 4};         // L1 array row offsets / NBATCH

  KArgs A; long acc = 0;
  auto addg = [&](const float* emb, int estride,
                  const int* isrc, int ss, int so, int c,
                  const int* insrc, int nstr, int no, int r,
                  const float* Ws, const float* Wn, float* outp, int ostride) {
    Seg& s = A.seg[A.n++];
    s.emb = emb; s.selfp = nullptr; s.neighp = nullptr;
    s.ids_s = isrc; s.ids_n = insrc;
    s.Ws = Ws; s.Wn = Wn; s.outp = outp;
    s.ss = ss; s.so = so; s.ns = nstr; s.no = no;
    s.estride = estride; s.ostride = ostride;
    s.c = c; s.r = r; s.rows = c * NBATCH; s.row_begin = (int)acc;
    acc += (long)c * NBATCH;
  };
  auto addd = [&](const float* selfp, const float* neighp, int c, int r,
                  const float* Ws, const float* Wn, float* outp, int ostride) {
    Seg& s = A.seg[A.n++];
    s.emb = nullptr; s.selfp = selfp; s.neighp = neighp;
    s.ids_s = nullptr; s.ids_n = nullptr;
    s.Ws = Ws; s.Wn = Wn; s.outp = outp;
    s.ss = 0; s.so = 0; s.ns = 0; s.no = 0; s.estride = 0; s.ostride = ostride;
    s.c = c; s.r = r; s.rows = c * NBATCH; s.row_begin = (int)acc;
    acc += (long)c * NBATCH;
  };

  // ---- launch 0: all level-0 (gather) pairs: schema1, schema0, random ----
  A.n = 0; acc = 0;
  for (int t = 0; t < 2; ++t)
    for (int k = 0; k < 4; ++k) {
      const float* emb = type_embed + (t * 2 + 1) * 100;  // (t, idx=1) slice
      if (k == 0)
        addg(emb, 400, nodeids, 1, 0, 1,
             neighbors, 2 * TOTALP, t * TOTALP + OFF1[k], FAN1[k],
             agg1_self, agg1_neigh, rp(t * S1r + CUM1[k] * NBATCH), 100);
      else
        addg(emb, 400, neighbors, 2 * TOTALP, t * TOTALP + OFF1[k - 1], C1[k],
             neighbors, 2 * TOTALP, t * TOTALP + OFF1[k], FAN1[k],
             agg1_self, agg1_neigh, rp(t * S1r + CUM1[k] * NBATCH), 100);
    }
  for (int t = 0; t < 2; ++t)
    for (int k = 0; k < 2; ++k) {
      const float* emb = type_embed + (t * 2 + 0) * 100;  // (t, idx=0) slice
      long obase = 294L * NBATCH + (long)t * 4 * NBATCH + (k == 0 ? 0 : 1) * NBATCH;
      if (k == 0)
        addg(emb, 400, nodeids, 1, 0, 1,
             neighbors, 2 * TOTALP, t * TOTALP + 0, 3,
             agg0_self, agg0_neigh, rp(obase), 100);
      else
        addg(emb, 400, neighbors, 2 * TOTALP, t * TOTALP + 0, 3,
             neighbors, 2 * TOTALP, t * TOTALP + 3, 5,
             agg0_self, agg0_neigh, rp(obase), 100);
    }
  for (int k = 0; k < 2; ++k) {
    long obase = 302L * NBATCH + (k == 0 ? 0 : 1) * NBATCH;
    if (k == 0)
      addg(rw_embed, 100, nodeids, 1, 0, 1,
           random_neighbors, 18, 0, 3, rand_self, rand_neigh, rp(obase), 100);
    else
      addg(rw_embed, 100, random_neighbors, 18, 0, 3,
           random_neighbors, 18, 3, 5, rand_self, rand_neigh, rp(obase), 100);
  }
  agg_kernel<<<dim3((unsigned)acc), dim3(128), 0, stream>>>(A);

  // ---- launch 1: schema1 L1, schema0 L1 (final), random L1 (final) ----
  A.n = 0; acc = 0;
  for (int t = 0; t < 2; ++t)
    for (int k = 0; k < 3; ++k)
      addd(rp(t * S1r + CUM1[k] * NBATCH), rp(t * S1r + CUM1[k + 1] * NBATCH),
           C1[k], FAN1[k], agg1_self + 5000, agg1_neigh + 5000,
           rp(t * S1r + 124L * NBATCH + CUM1b[k] * NBATCH), 100);
  for (int t = 0; t < 2; ++t)
    addd(rp(294L * NBATCH + (long)t * 4 * NBATCH),
         rp(294L * NBATCH + (long)t * 4 * NBATCH + NBATCH),
         1, 3, agg0_self + 5000, agg0_neigh + 5000, spec_f + t * 100, 400);
  addd(rp(302L * NBATCH), rp(303L * NBATCH), 1, 3,
       rand_self + 5000, rand_neigh + 5000, rview_f, 100);
  agg_kernel<<<dim3((unsigned)acc), dim3(128), 0, stream>>>(A);

  // ---- launch 2: schema1 L2 ----
  A.n = 0; acc = 0;
  for (int t = 0; t < 2; ++t)
    for (int k = 0; k < 2; ++k)
      addd(rp(t * S1r + 124L * NBATCH + CUM1b[k] * NBATCH),
           rp(t * S1r + 124L * NBATCH + CUM1b[k + 1] * NBATCH),
           C1[k], FAN1[k], agg1_self + 10000, agg1_neigh + 10000,
           rp(t * S1r + 143L * NBATCH + (k == 0 ? 0 : 1) * NBATCH), 100);
  agg_kernel<<<dim3((unsigned)acc), dim3(128), 0, stream>>>(A);

  // ---- launch 3: schema1 L3 (final -> spec view 1) ----
  A.n = 0; acc = 0;
  for (int t = 0; t < 2; ++t)
    addd(rp(t * S1r + 143L * NBATCH), rp(t * S1r + 144L * NBATCH),
         1, 3, agg1_self + 15000, agg1_neigh + 15000,
         spec_f + 200 + t * 100, 400);
  agg_kernel<<<dim3((unsigned)acc), dim3(128), 0, stream>>>(A);

  // ---- launch 4: attention + epilogue ----
  attn_final_kernel<<<dim3(NBATCH), dim3(128), 0, stream>>>(
      spec_f, rview_f, nodeids, edgetype, base_embed, reflect,
      vWq, vWk, vWv, vWf, vg, vb, mWq, mWk, mWv, mWf, mg, mb,
      (float*)d_out);
}

// Round 3
// 657.454 us; speedup vs baseline: 1.3185x; 1.3185x over previous
//
#include <hip/hip_runtime.h>
#include <math.h>

// ---------------------------------------------------------------------------
// HybridGNN on MI355X — R3 (R2 + compile fix: removed out-of-scope (void)half).
// agg v2: 32 rows/block, W staged in LDS once per block (amortized over 32
//         rows), float4 gathers, 4x4 register-tiled matvec (16 FMA / 5 LDS).
// attn v2: per-b block, but all weight matvecs read W from LDS chunks staged
//          with coalesced float4 loads; 4-col register tiling.
// Workspace layout identical to R1 (rows of 100 f32).
// ---------------------------------------------------------------------------

#define NBATCH 512
#define TOTALP 1086
#define RPB 32      // rows per agg block (all segment row counts divide by 32)
#define XSTR 204    // xs LDS row stride (floats), breaks 800-stride bank alias
#define WSTR 112    // W LDS row stride: [0:50)=Ws, [56:106)=Wn, rest zero pad

struct Seg {
  const float* emb;     // gather mode embedding base (null => dense mode)
  const float* selfp;   // dense self rows [N][100]
  const float* neighp;  // dense neighbor rows [N*r][100]
  const int*   ids_s;   // gather: self id array
  const int*   ids_n;   // gather: neighbor id array
  const float* Ws;      // [100][50]
  const float* Wn;      // [100][50]
  float*       outp;    // out row j at outp + j*ostride
  int ss, so;           // self id per-b stride, offset
  int ns, no;           // neigh id per-b stride, offset
  int estride;          // node stride in emb (elements)
  int ostride;
  int c;                // self rows per batch element
  int r;                // fanout
  int blk_begin;        // prefix in fused BLOCK space
};

struct KArgs { Seg seg[14]; int n; };

__global__ __launch_bounds__(256) void agg_kernel(KArgs P) {
  __shared__ float Wsh[100 * WSTR];     // 44.8 KB
  __shared__ float xsh[RPB * XSTR];     // 26.1 KB  xs[row][0:100]=s, [100:200]=m
  __shared__ int   ids_s_sh[RPB];
  __shared__ int   ids_n_sh[RPB * 9];

  const int blk = blockIdx.x, tid = threadIdx.x;
  int si = 0;
  for (int i = 1; i < P.n; ++i)
    if (blk >= P.seg[i].blk_begin) si = i;
  const Seg sg = P.seg[si];
  const int j0 = (blk - sg.blk_begin) * RPB;
  const int c = sg.c, r = sg.r;

  // ---- Phase A: stage W into LDS (and zero pad cols) ----
  for (int u = tid; u < 5000; u += 256) {
    int e = u / 50, cc = u - e * 50;
    Wsh[e * WSTR + cc]      = sg.Ws[u];
    Wsh[e * WSTR + 56 + cc] = sg.Wn[u];
  }
  for (int u = tid; u < 1200; u += 256) {
    int e = u / 12, p = u - e * 12;
    Wsh[e * WSTR + (p < 6 ? 50 + p : 100 + p)] = 0.f;
  }
  // ---- ids staging (gather mode) ----
  if (sg.emb) {
    if (tid < RPB) {
      int j = j0 + tid, b = j / c, pos = j - b * c;
      ids_s_sh[tid] = sg.ids_s[(long)b * sg.ss + sg.so + pos];
    }
    for (int u = tid; u < RPB * r; u += 256) {
      int row = u / r, q = u - row * r;
      int j = j0 + row, b = j / c, pos = j - b * c;
      ids_n_sh[u] = sg.ids_n[(long)b * sg.ns + sg.no + pos * r + q];
    }
  }
  __syncthreads();

  // ---- Phase B: gather/load X into LDS ----
  const float rinv = 1.f / (float)r;
  for (int u = tid; u < RPB * 25; u += 256) {
    int row = u / 25, q4 = (u - row * 25) * 4;
    float sx, sy, sz, sw, mx = 0.f, my = 0.f, mz = 0.f, mw = 0.f;
    if (sg.emb) {
      const float4 s4 = *(const float4*)(sg.emb + (long)ids_s_sh[row] * sg.estride + q4);
      sx = s4.x; sy = s4.y; sz = s4.z; sw = s4.w;
      for (int rr = 0; rr < r; ++rr) {
        const float4 t = *(const float4*)(sg.emb + (long)ids_n_sh[row * r + rr] * sg.estride + q4);
        mx += t.x; my += t.y; mz += t.z; mw += t.w;
      }
    } else {
      long j = j0 + row;
      const float4 s4 = *(const float4*)(sg.selfp + j * 100 + q4);
      sx = s4.x; sy = s4.y; sz = s4.z; sw = s4.w;
      for (int rr = 0; rr < r; ++rr) {
        const float4 t = *(const float4*)(sg.neighp + (j * r + rr) * 100 + q4);
        mx += t.x; my += t.y; mz += t.z; mw += t.w;
      }
    }
    float4 sv; sv.x = sx; sv.y = sy; sv.z = sz; sv.w = sw;
    float4 mv; mv.x = mx * rinv; mv.y = my * rinv; mv.z = mz * rinv; mv.w = mw * rinv;
    *(float4*)&xsh[row * XSTR + q4]       = sv;
    *(float4*)&xsh[row * XSTR + 100 + q4] = mv;
  }
  __syncthreads();

  // ---- Phase C: 4 rows x 4 cols register-tiled matvec ----
  if (tid < 224) {
    const int rg = tid / 28, cq = tid - rg * 28;
    const int wcol = 4 * cq;
    const int xoff = (cq < 14) ? 0 : 100;
    float acc[4][4];
#pragma unroll
    for (int i = 0; i < 4; ++i) { acc[i][0] = acc[i][1] = acc[i][2] = acc[i][3] = 0.f; }
    const float* xb = &xsh[(rg * 4) * XSTR + xoff];
#pragma unroll 4
    for (int e = 0; e < 100; ++e) {
      const float4 wv = *(const float4*)&Wsh[e * WSTR + wcol];
#pragma unroll
      for (int i = 0; i < 4; ++i) {
        const float a = xb[i * XSTR + e];
        acc[i][0] = fmaf(a, wv.x, acc[i][0]);
        acc[i][1] = fmaf(a, wv.y, acc[i][1]);
        acc[i][2] = fmaf(a, wv.z, acc[i][2]);
        acc[i][3] = fmaf(a, wv.w, acc[i][3]);
      }
    }
    const int cl = (cq < 14) ? cq : cq - 14;       // quad index within half
    if (cl < 13) {
      const int cbase = (cq < 14 ? 0 : 50) + 4 * cl;
      for (int i = 0; i < 4; ++i) {
        const long j = j0 + rg * 4 + i;
        float* op = sg.outp + j * (long)sg.ostride + cbase;
        if (cl < 12) {
          float4 o;
          o.x = fmaxf(acc[i][0], 0.f); o.y = fmaxf(acc[i][1], 0.f);
          o.z = fmaxf(acc[i][2], 0.f); o.w = fmaxf(acc[i][3], 0.f);
          *(float4*)op = o;
        } else {   // cols 48,49 (or 98,99)
          op[0] = fmaxf(acc[i][0], 0.f);
          op[1] = fmaxf(acc[i][1], 0.f);
        }
      }
    }
  }
}

// ---------------------------------------------------------------------------
// Attention step, W staged through LDS chunks.  x rows at xs[base+i*rs+d].
// ---------------------------------------------------------------------------
__device__ __forceinline__ void attn_step(
    float* xs, int base, int rs, int n,
    const float* Wq, const float* Wk, const float* Wv, const float* Wf,
    const float* g, const float* bb,
    float* ln, float* qq, float* kk, float* vv, float* ot,
    float* sc, float* musd, float* wsh, int tid)
{
  if (tid < n) {
    float mu = 0.f;
    for (int d = 0; d < 100; ++d) mu += xs[base + tid * rs + d];
    mu *= 0.01f;
    float var = 0.f;
    for (int d = 0; d < 100; ++d) {
      float t = xs[base + tid * rs + d] - mu; var = fmaf(t, t, var);
    }
    var *= 0.01f;
    musd[tid * 2]     = mu;
    musd[tid * 2 + 1] = rsqrtf(var + 1e-6f);
  }
  __syncthreads();
  for (int o = tid; o < n * 100; o += 128) {
    int i = o / 100, d = o - i * 100;
    ln[o] = (xs[base + i * rs + d] - musd[i * 2]) * musd[i * 2 + 1] * g[d] + bb[d];
  }
  __syncthreads();

  // ---- q,k,v: thread owns (row i, 4 cols d4), W chunks of 50 e-rows ----
  const bool act = tid < n * 25;
  const int  i   = tid / 25;
  const int  d4  = 4 * (tid - i * 25);
  float aq[4] = {0,0,0,0}, ak[4] = {0,0,0,0}, av[4] = {0,0,0,0};
  for (int ch = 0; ch < 2; ++ch) {
    for (int u = tid; u < 1250; u += 128) {
      int el = u / 25, dd = 4 * (u - el * 25);
      *(float4*)&wsh[el * 300 + dd]       = *(const float4*)&Wq[(ch * 50 + el) * 100 + dd];
      *(float4*)&wsh[el * 300 + 100 + dd] = *(const float4*)&Wk[(ch * 50 + el) * 100 + dd];
      *(float4*)&wsh[el * 300 + 200 + dd] = *(const float4*)&Wv[(ch * 50 + el) * 100 + dd];
    }
    __syncthreads();
    if (act) {
      for (int el = 0; el < 50; ++el) {
        const float lnv = ln[i * 100 + ch * 50 + el];
        const float xv  = xs[base + i * rs + ch * 50 + el];
        const float4 wq = *(const float4*)&wsh[el * 300 + d4];
        const float4 wk = *(const float4*)&wsh[el * 300 + 100 + d4];
        const float4 wv = *(const float4*)&wsh[el * 300 + 200 + d4];
        aq[0] = fmaf(lnv, wq.x, aq[0]); aq[1] = fmaf(lnv, wq.y, aq[1]);
        aq[2] = fmaf(lnv, wq.z, aq[2]); aq[3] = fmaf(lnv, wq.w, aq[3]);
        ak[0] = fmaf(xv,  wk.x, ak[0]); ak[1] = fmaf(xv,  wk.y, ak[1]);
        ak[2] = fmaf(xv,  wk.z, ak[2]); ak[3] = fmaf(xv,  wk.w, ak[3]);
        av[0] = fmaf(xv,  wv.x, av[0]); av[1] = fmaf(xv,  wv.y, av[1]);
        av[2] = fmaf(xv,  wv.z, av[2]); av[3] = fmaf(xv,  wv.w, av[3]);
      }
    }
    __syncthreads();
  }
  if (act) {
#pragma unroll
    for (int jj = 0; jj < 4; ++jj) {
      qq[i * 100 + d4 + jj] = aq[jj];
      kk[i * 100 + d4 + jj] = ak[jj];
      vv[i * 100 + d4 + jj] = av[jj];
    }
  }
  __syncthreads();

  if (tid < n * n) {
    int qi = tid / n, u = tid - qi * n;
    float s = 0.f;
    for (int d = 0; d < 100; ++d) s = fmaf(qq[qi * 100 + d], kk[u * 100 + d], s);
    sc[tid] = s * 0.1f;
  }
  __syncthreads();
  if (tid < n) {
    float mx = sc[tid * n];
    for (int u = 1; u < n; ++u) mx = fmaxf(mx, sc[tid * n + u]);
    float sm = 0.f;
    for (int u = 0; u < n; ++u) {
      float e = expf(sc[tid * n + u] - mx); sc[tid * n + u] = e; sm += e;
    }
    float inv = 1.f / sm;
    for (int u = 0; u < n; ++u) sc[tid * n + u] *= inv;
  }
  __syncthreads();
  for (int o = tid; o < n * 100; o += 128) {
    int ii = o / 100, d = o - ii * 100;
    float a = 0.f;
    for (int u = 0; u < n; ++u) a = fmaf(sc[ii * n + u], vv[u * 100 + d], a);
    ot[o] = a;
  }
  __syncthreads();

  // ---- Wf + residual, chunked through LDS ----
  float af[4] = {0,0,0,0};
  for (int ch = 0; ch < 2; ++ch) {
    for (int u = tid; u < 1250; u += 128) {
      int el = u / 25, dd = 4 * (u - el * 25);
      *(float4*)&wsh[el * 100 + dd] = *(const float4*)&Wf[(ch * 50 + el) * 100 + dd];
    }
    __syncthreads();
    if (act) {
      for (int el = 0; el < 50; ++el) {
        const float ov = ot[i * 100 + ch * 50 + el];
        const float4 wf = *(const float4*)&wsh[el * 100 + d4];
        af[0] = fmaf(ov, wf.x, af[0]); af[1] = fmaf(ov, wf.y, af[1]);
        af[2] = fmaf(ov, wf.z, af[2]); af[3] = fmaf(ov, wf.w, af[3]);
      }
    }
    __syncthreads();
  }
  if (act) {
#pragma unroll
    for (int jj = 0; jj < 4; ++jj)
      xs[base + i * rs + d4 + jj] += af[jj];
  }
  __syncthreads();
}

__global__ __launch_bounds__(128) void attn_final_kernel(
    const float* __restrict__ spec, const float* __restrict__ rview,
    const int* __restrict__ nodeids, const int* __restrict__ edgetype,
    const float* __restrict__ base_embed, const float* __restrict__ reflect,
    const float* vWq, const float* vWk, const float* vWv, const float* vWf,
    const float* vg, const float* vb,
    const float* mWq, const float* mWk, const float* mWv, const float* mWf,
    const float* mg, const float* mb,
    float* __restrict__ out)
{
  __shared__ float xs[600], ln[300], qq[300], kk[300], vv[300], ot[300];
  __shared__ float sc[9], musd[6], r200[200], pooled[200], nrmv[1];
  __shared__ float wsh[15000];
  const int b = blockIdx.x, tid = threadIdx.x;

  for (int o = tid; o < 600; o += 128) {
    int v = o / 200, rem = o - v * 200;
    xs[o] = (v < 2) ? spec[(long)b * 400 + o] : rview[(long)b * 100 + (rem % 100)];
  }
  __syncthreads();

  for (int v = 0; v < 3; ++v)
    attn_step(xs, v * 200, 100, 2, vWq, vWk, vWv, vWf, vg, vb,
              ln, qq, kk, vv, ot, sc, musd, wsh, tid);
  for (int t = 0; t < 2; ++t)
    attn_step(xs, t * 100, 200, 3, mWq, mWk, mWv, mWf, mg, mb,
              ln, qq, kk, vv, ot, sc, musd, wsh, tid);

  for (int o = tid; o < 200; o += 128)
    pooled[o] = (xs[o] + xs[200 + o] + xs[400 + o]) * (1.f / 3.f);
  __syncthreads();

  const int  et  = edgetype[NBATCH + b];
  const long nid = nodeids[b];

  float ar[4] = {0,0,0,0};
  if (tid < 50) {
    const float4 be = *(const float4*)&base_embed[nid * 200 + 4 * tid];
    ar[0] = be.x; ar[1] = be.y; ar[2] = be.z; ar[3] = be.w;
  }
  for (int ch = 0; ch < 2; ++ch) {
    for (int u = tid; u < 2500; u += 128) {
      int dl = u / 50, oo = 4 * (u - dl * 50);
      *(float4*)&wsh[dl * 200 + oo] =
          *(const float4*)&reflect[((long)et * 100 + ch * 50 + dl) * 200 + oo];
    }
    __syncthreads();
    if (tid < 50) {
      for (int dl = 0; dl < 50; ++dl) {
        const float pv = pooled[et * 100 + ch * 50 + dl];
        const float4 rv = *(const float4*)&wsh[dl * 200 + 4 * tid];
        ar[0] = fmaf(pv, rv.x, ar[0]); ar[1] = fmaf(pv, rv.y, ar[1]);
        ar[2] = fmaf(pv, rv.z, ar[2]); ar[3] = fmaf(pv, rv.w, ar[3]);
      }
    }
    __syncthreads();
  }
  if (tid < 50) {
    r200[4 * tid]     = ar[0]; r200[4 * tid + 1] = ar[1];
    r200[4 * tid + 2] = ar[2]; r200[4 * tid + 3] = ar[3];
  }
  __syncthreads();
  if (tid == 0) {
    float ss = 0.f;
    for (int o = 0; o < 200; ++o) ss = fmaf(r200[o], r200[o], ss);
    nrmv[0] = 1.f / fmaxf(sqrtf(ss), 1e-12f);
  }
  __syncthreads();
  for (int o = tid; o < 200; o += 128)
    out[(long)b * 200 + o] = r200[o] * nrmv[0];
}

// ---------------------------------------------------------------------------
extern "C" void kernel_launch(void* const* d_in, const int* in_sizes, int n_in,
                              void* d_out, int out_size, void* d_ws, size_t ws_size,
                              hipStream_t stream) {
  (void)in_sizes; (void)n_in; (void)out_size; (void)ws_size;
  const int*   nodeids          = (const int*)d_in[0];
  const int*   edgetype         = (const int*)d_in[1];
  const int*   neighbors        = (const int*)d_in[2];
  const int*   random_neighbors = (const int*)d_in[3];
  const float* base_embed       = (const float*)d_in[4];
  const float* type_embed       = (const float*)d_in[5];
  const float* rw_embed         = (const float*)d_in[6];
  const float* reflect          = (const float*)d_in[7];
  const float* agg0_self        = (const float*)d_in[8];
  const float* agg0_neigh       = (const float*)d_in[9];
  const float* agg1_self        = (const float*)d_in[10];
  const float* agg1_neigh       = (const float*)d_in[11];
  const float* rand_self        = (const float*)d_in[12];
  const float* rand_neigh       = (const float*)d_in[13];
  const float* vWq = (const float*)d_in[14];
  const float* vWk = (const float*)d_in[15];
  const float* vWv = (const float*)d_in[16];
  const float* vWf = (const float*)d_in[17];
  const float* vg  = (const float*)d_in[18];
  const float* vb  = (const float*)d_in[19];
  const float* mWq = (const float*)d_in[20];
  const float* mWk = (const float*)d_in[21];
  const float* mWv = (const float*)d_in[22];
  const float* mWf = (const float*)d_in[23];
  const float* mg  = (const float*)d_in[24];
  const float* mb  = (const float*)d_in[25];

  float* ws = (float*)d_ws;
  const long S1r = 147L * NBATCH;                 // schema1 rows per t
  auto rp = [&](long rows) { return ws + rows * 100; };
  float* spec_f  = ws + 306L * NBATCH * 100;      // [B][2][2][100]
  float* rview_f = spec_f + (long)NBATCH * 400;   // [B][100]

  const int  OFF1[4] = {18, 21, 36, 141};
  const int  FAN1[4] = {3, 5, 7, 9};
  const int  C1[4]   = {1, 3, 15, 105};
  const long CUM1[4]  = {0, 1, 4, 19};
  const long CUM1b[3] = {0, 1, 4};

  KArgs A; long acc = 0;   // acc in BLOCKS (32 rows each)
  auto addg = [&](const float* emb, int estride,
                  const int* isrc, int ss, int so, int c,
                  const int* insrc, int nstr, int no, int r,
                  const float* Ws, const float* Wn, float* outp, int ostride) {
    Seg& s = A.seg[A.n++];
    s.emb = emb; s.selfp = nullptr; s.neighp = nullptr;
    s.ids_s = isrc; s.ids_n = insrc;
    s.Ws = Ws; s.Wn = Wn; s.outp = outp;
    s.ss = ss; s.so = so; s.ns = nstr; s.no = no;
    s.estride = estride; s.ostride = ostride;
    s.c = c; s.r = r; s.blk_begin = (int)acc;
    acc += (long)c * NBATCH / RPB;
  };
  auto addd = [&](const float* selfp, const float* neighp, int c, int r,
                  const float* Ws, const float* Wn, float* outp, int ostride) {
    Seg& s = A.seg[A.n++];
    s.emb = nullptr; s.selfp = selfp; s.neighp = neighp;
    s.ids_s = nullptr; s.ids_n = nullptr;
    s.Ws = Ws; s.Wn = Wn; s.outp = outp;
    s.ss = 0; s.so = 0; s.ns = 0; s.no = 0; s.estride = 0; s.ostride = ostride;
    s.c = c; s.r = r; s.blk_begin = (int)acc;
    acc += (long)c * NBATCH / RPB;
  };

  // ---- launch 0: all level-0 (gather) pairs ----
  A.n = 0; acc = 0;
  for (int t = 0; t < 2; ++t)
    for (int k = 0; k < 4; ++k) {
      const float* emb = type_embed + (t * 2 + 1) * 100;
      if (k == 0)
        addg(emb, 400, nodeids, 1, 0, 1,
             neighbors, 2 * TOTALP, t * TOTALP + OFF1[k], FAN1[k],
             agg1_self, agg1_neigh, rp(t * S1r + CUM1[k] * NBATCH), 100);
      else
        addg(emb, 400, neighbors, 2 * TOTALP, t * TOTALP + OFF1[k - 1], C1[k],
             neighbors, 2 * TOTALP, t * TOTALP + OFF1[k], FAN1[k],
             agg1_self, agg1_neigh, rp(t * S1r + CUM1[k] * NBATCH), 100);
    }
  for (int t = 0; t < 2; ++t)
    for (int k = 0; k < 2; ++k) {
      const float* emb = type_embed + (t * 2 + 0) * 100;
      long obase = 294L * NBATCH + (long)t * 4 * NBATCH + (k == 0 ? 0 : 1) * NBATCH;
      if (k == 0)
        addg(emb, 400, nodeids, 1, 0, 1,
             neighbors, 2 * TOTALP, t * TOTALP + 0, 3,
             agg0_self, agg0_neigh, rp(obase), 100);
      else
        addg(emb, 400, neighbors, 2 * TOTALP, t * TOTALP + 0, 3,
             neighbors, 2 * TOTALP, t * TOTALP + 3, 5,
             agg0_self, agg0_neigh, rp(obase), 100);
    }
  for (int k = 0; k < 2; ++k) {
    long obase = 302L * NBATCH + (k == 0 ? 0 : 1) * NBATCH;
    if (k == 0)
      addg(rw_embed, 100, nodeids, 1, 0, 1,
           random_neighbors, 18, 0, 3, rand_self, rand_neigh, rp(obase), 100);
    else
      addg(rw_embed, 100, random_neighbors, 18, 0, 3,
           random_neighbors, 18, 3, 5, rand_self, rand_neigh, rp(obase), 100);
  }
  agg_kernel<<<dim3((unsigned)acc), dim3(256), 0, stream>>>(A);

  // ---- launch 1: schema1 L1, schema0 L1 (final), random L1 (final) ----
  A.n = 0; acc = 0;
  for (int t = 0; t < 2; ++t)
    for (int k = 0; k < 3; ++k)
      addd(rp(t * S1r + CUM1[k] * NBATCH), rp(t * S1r + CUM1[k + 1] * NBATCH),
           C1[k], FAN1[k], agg1_self + 5000, agg1_neigh + 5000,
           rp(t * S1r + 124L * NBATCH + CUM1b[k] * NBATCH), 100);
  for (int t = 0; t < 2; ++t)
    addd(rp(294L * NBATCH + (long)t * 4 * NBATCH),
         rp(294L * NBATCH + (long)t * 4 * NBATCH + NBATCH),
         1, 3, agg0_self + 5000, agg0_neigh + 5000, spec_f + t * 100, 400);
  addd(rp(302L * NBATCH), rp(303L * NBATCH), 1, 3,
       rand_self + 5000, rand_neigh + 5000, rview_f, 100);
  agg_kernel<<<dim3((unsigned)acc), dim3(256), 0, stream>>>(A);

  // ---- launch 2: schema1 L2 ----
  A.n = 0; acc = 0;
  for (int t = 0; t < 2; ++t)
    for (int k = 0; k < 2; ++k)
      addd(rp(t * S1r + 124L * NBATCH + CUM1b[k] * NBATCH),
           rp(t * S1r + 124L * NBATCH + CUM1b[k + 1] * NBATCH),
           C1[k], FAN1[k], agg1_self + 10000, agg1_neigh + 10000,
           rp(t * S1r + 143L * NBATCH + (k == 0 ? 0 : 1) * NBATCH), 100);
  agg_kernel<<<dim3((unsigned)acc), dim3(256), 0, stream>>>(A);

  // ---- launch 3: schema1 L3 (final -> spec view 1) ----
  A.n = 0; acc = 0;
  for (int t = 0; t < 2; ++t)
    addd(rp(t * S1r + 143L * NBATCH), rp(t * S1r + 144L * NBATCH),
         1, 3, agg1_self + 15000, agg1_neigh + 15000,
         spec_f + 200 + t * 100, 400);
  agg_kernel<<<dim3((unsigned)acc), dim3(256), 0, stream>>>(A);

  // ---- launch 4: attention + epilogue ----
  attn_final_kernel<<<dim3(NBATCH), dim3(128), 0, stream>>>(
      spec_f, rview_f, nodeids, edgetype, base_embed, reflect,
      vWq, vWk, vWv, vWf, vg, vb, mWq, mWk, mWv, mWf, mg, mb,
      (float*)d_out);
}